// Round 2
// baseline (148.078 us; speedup 1.0000x reference)
//
#include <hip/hip_runtime.h>

#define BB 256
#define TT 1024
#define VV 64
#define LL 64
#define LOG2E 1.4426950408889634f
#define LN2   0.6931471805599453f

__device__ __forceinline__ int   f2i(float x) { return __float_as_int(x); }
__device__ __forceinline__ float i2f(int x)   { return __int_as_float(x); }

// lgkm-only barrier: orders LDS producer->consumer WITHOUT draining vmcnt,
// so the producer's register-prefetch global loads stay in flight across
// windows (T4). "memory" clobber pins loads/stores on both sides.
__device__ __forceinline__ void barrier_lds() {
  asm volatile("s_waitcnt lgkmcnt(0)" ::: "memory");
  __builtin_amdgcn_s_barrier();
}

// wave-wide max of non-negative values (0 identity), result broadcast
__device__ __forceinline__ float wave_max63(float x) {
  x = fmaxf(x, i2f(__builtin_amdgcn_update_dpp(0, f2i(x), 0x111, 0xF, 0xF, true)));
  x = fmaxf(x, i2f(__builtin_amdgcn_update_dpp(0, f2i(x), 0x112, 0xF, 0xF, true)));
  x = fmaxf(x, i2f(__builtin_amdgcn_update_dpp(0, f2i(x), 0x114, 0xF, 0xF, true)));
  x = fmaxf(x, i2f(__builtin_amdgcn_update_dpp(0, f2i(x), 0x118, 0xF, 0xF, true)));
  x = fmaxf(x, i2f(__builtin_amdgcn_update_dpp(0, f2i(x), 0x142, 0xF, 0xF, true)));
  x = fmaxf(x, i2f(__builtin_amdgcn_update_dpp(0, f2i(x), 0x143, 0xF, 0xF, true)));
  return i2f(__builtin_amdgcn_readlane(f2i(x), 63));
}

// ---------- 2-wave producer/consumer kernel: block b = batch element b ----------
// Wave 1 (producer): reg-stages raw logits (global_load_dwordx4, 3-window-deep
// static register ring via x3 loop unroll -> compiler emits counted vmcnt,
// never 0 in-loop), exps ONCE, ds_writes the exp'd window + a packed blank
// row (cexpb), and accumulates the row-LSE with a VALU-only DPP reduce.
// Wave 0 (consumer): per window 16 per-lane g-gathers + 4 uniform b128 reads
// of packed c — ZERO exps, zero vmem — then renorm + 16 DP steps. Renorm
// target 2^60 (R9-validated); one lgkm-only barrier per window.
extern "C" __global__ void __launch_bounds__(128, 1)
ctc_fused(const int* __restrict__ labels, const float* __restrict__ logits,
          const int* __restrict__ mask, float* __restrict__ out) {
  __shared__ __align__(16) float ebuf[2][16][VV];   // 8 KB exp'd emissions, 2 windows
  __shared__ __align__(16) float cexpb[2][16];      // packed blank emissions e^{logit[t][0]}
  __shared__ float lsePart;
  const int b = blockIdx.x;
  const int tid = threadIdx.x;
  const int lane = tid & 63;
  const int wv = tid >> 6;

  const float* lg = logits + (size_t)b * TT * VV;

  // both waves compute len (redundant, preamble-only)
  int lsum = 0;
  const int* mrow = mask + b * TT;
#pragma unroll
  for (int k = 0; k < TT / 64; ++k) lsum += mrow[lane + (k << 6)];
#pragma unroll
  for (int off = 32; off; off >>= 1) lsum += __shfl_xor(lsum, off);
  int len = __builtin_amdgcn_readfirstlane(lsum);
  len = len < 1 ? 1 : (len > TT ? TT : len);
  const int nwin = (len + 15) >> 4;      // windows actually needed (<= 64)

  // wave-0-only DP state
  int lab = 0, lab_len = 0;
  float sk = 0.0f;
  float A0 = 0.0f, A1 = 0.0f, A2 = 0.0f;
  int ctot = 0;
  if (wv == 0) {
    lab = labels[b * LL + lane] & 63;             // label for state 2*lane+1
    lab_len = (int)__popcll(__ballot(lab != 0));
    const int plab = __builtin_amdgcn_update_dpp(0, lab, 0x138, 0xF, 0xF, false);
    sk = (lab != 0 && lab != plab) ? 1.0f : 0.0f; // allow_skip
    A0 = (lane == 0) ? 1.0f : 0.0f;               // t=0 runs as a normal step
    __builtin_amdgcn_s_setprio(1);                // consumer is critical path
  }

  // producer geometry: one dwordx4 load covers 4 rows x 64 cols.
  // lane -> row-in-load (lane>>4), col base ((lane&15)*4).
  const int prow = lane >> 4;
  const int pcol = (lane & 15) << 2;
  const float* gbase = lg + (size_t)(prow * VV) + pcol;
  float acc = 0.0f;

  float4 ra0{0,0,0,0}, ra1{0,0,0,0}, ra2{0,0,0,0}, ra3{0,0,0,0};
  float4 rb0{0,0,0,0}, rb1{0,0,0,0}, rb2{0,0,0,0}, rb3{0,0,0,0};
  float4 rc0{0,0,0,0}, rc1{0,0,0,0}, rc2{0,0,0,0}, rc3{0,0,0,0};

// issue the 4 loads of window WN into register set S (offsets fold to imm)
#define ISSUE(WN, S) { \
    const float* p_ = gbase + ((WN) << 10); \
    S##0 = *(const float4*)(p_); \
    S##1 = *(const float4*)(p_ + 256); \
    S##2 = *(const float4*)(p_ + 512); \
    S##3 = *(const float4*)(p_ + 768); \
  }

// exp + LDS write + row-LSE for one 4-row load of window WN
#define PEMIT(WN, LD, V) { \
    const float e0 = __builtin_amdgcn_exp2f((V).x * LOG2E); \
    const float e1 = __builtin_amdgcn_exp2f((V).y * LOG2E); \
    const float e2 = __builtin_amdgcn_exp2f((V).z * LOG2E); \
    const float e3 = __builtin_amdgcn_exp2f((V).w * LOG2E); \
    float4 ev; ev.x = e0; ev.y = e1; ev.z = e2; ev.w = e3; \
    *(float4*)&ebuf[(WN) & 1][((LD) << 2) + prow][pcol] = ev; \
    if ((lane & 15) == 0) cexpb[(WN) & 1][((LD) << 2) + prow] = e0; \
    float s = (e0 + e1) + (e2 + e3); \
    s += i2f(__builtin_amdgcn_update_dpp(0, f2i(s), 0x111, 0xF, 0xF, true)); \
    s += i2f(__builtin_amdgcn_update_dpp(0, f2i(s), 0x112, 0xF, 0xF, true)); \
    s += i2f(__builtin_amdgcn_update_dpp(0, f2i(s), 0x114, 0xF, 0xF, true)); \
    s += i2f(__builtin_amdgcn_update_dpp(0, f2i(s), 0x118, 0xF, 0xF, true)); \
    if ((lane & 15) == 15 && ((((WN) << 4) + ((LD) << 2) + prow) < len)) acc += __logf(s); \
  }

#define PRODUCE(WN, S) { PEMIT(WN, 0, S##0) PEMIT(WN, 1, S##1) PEMIT(WN, 2, S##2) PEMIT(WN, 3, S##3) }

  // renorm to 2^60 (R9-validated): flush floor ~186 log2 below running max,
  // overflow headroom +67 log2 per 16-step window.
#define RENORM() { \
    const float mxv = wave_max63(fmaxf(fmaxf(A0, A1), A2)); \
    const int eb_ = (f2i(mxv) >> 23) & 255; \
    int kk = (eb_ > 0 && eb_ < 255) ? (187 - eb_) : 0; \
    kk = kk > 126 ? 126 : (kk < -126 ? -126 : kk); \
    ctot += kk; \
    const float sc = i2f((127 + kk) << 23); \
    A0 *= sc; A1 *= sc; A2 *= sc; \
  }

#define STEPU(U) { \
    const float A1p = i2f(__builtin_amdgcn_update_dpp(0, f2i(A1), 0x138, 0xF, 0xF, false)); \
    const float nA0 = c##U * (A0 + A1p); \
    const float nA1 = g##U * fmaf(sk, A1p, A0 + A1); \
    A2 = c##U * (A2 + A1); \
    A0 = nA0; A1 = nA1; \
  }

#define STEPM(U) { \
    const float A1p = i2f(__builtin_amdgcn_update_dpp(0, f2i(A1), 0x138, 0xF, 0xF, false)); \
    const float nA0 = c##U * (A0 + A1p); \
    const float nA1 = g##U * fmaf(sk, A1p, A0 + A1); \
    const float nA2 = c##U * (A2 + A1); \
    const bool act = (tbase + (U)) < len; \
    A0 = act ? nA0 : A0; A1 = act ? nA1 : A1; A2 = act ? nA2 : A2; \
  }

#define CONSUME(W) { \
    const float* eb = &ebuf[(W) & 1][0][0]; \
    float g0,g1,g2,g3,g4,g5,g6,g7,g8,g9,g10,g11,g12,g13,g14,g15; \
    g0  = eb[(0<<6)  + lab]; g1  = eb[(1<<6)  + lab]; g2  = eb[(2<<6)  + lab]; g3  = eb[(3<<6)  + lab]; \
    g4  = eb[(4<<6)  + lab]; g5  = eb[(5<<6)  + lab]; g6  = eb[(6<<6)  + lab]; g7  = eb[(7<<6)  + lab]; \
    g8  = eb[(8<<6)  + lab]; g9  = eb[(9<<6)  + lab]; g10 = eb[(10<<6) + lab]; g11 = eb[(11<<6) + lab]; \
    g12 = eb[(12<<6) + lab]; g13 = eb[(13<<6) + lab]; g14 = eb[(14<<6) + lab]; g15 = eb[(15<<6) + lab]; \
    const float4* cp = (const float4*)cexpb[(W) & 1]; \
    const float4 cva = cp[0], cvb = cp[1], cvc = cp[2], cvd = cp[3]; \
    const float c0 = cva.x,  c1 = cva.y,  c2 = cva.z,  c3 = cva.w; \
    const float c4 = cvb.x,  c5 = cvb.y,  c6 = cvb.z,  c7 = cvb.w; \
    const float c8 = cvc.x,  c9 = cvc.y,  c10 = cvc.z, c11 = cvc.w; \
    const float c12 = cvd.x, c13 = cvd.y, c14 = cvd.z, c15 = cvd.w; \
    RENORM() \
    const int tbase = (W) << 4; \
    if (tbase + 16 <= len) { \
      STEPU(0)  STEPU(1)  STEPU(2)  STEPU(3)  STEPU(4)  STEPU(5)  STEPU(6)  STEPU(7) \
      STEPU(8)  STEPU(9)  STEPU(10) STEPU(11) STEPU(12) STEPU(13) STEPU(14) STEPU(15) \
    } else { \
      STEPM(0)  STEPM(1)  STEPM(2)  STEPM(3)  STEPM(4)  STEPM(5)  STEPM(6)  STEPM(7) \
      STEPM(8)  STEPM(9)  STEPM(10) STEPM(11) STEPM(12) STEPM(13) STEPM(14) STEPM(15) \
    } \
  }

// one window: barrier, then producer makes window W+1 (consuming reg set S,
// refilling it with window W+4's loads) while consumer eats window W.
#define BODY(W, S) { \
    barrier_lds(); \
    if (wv != 0) { \
      if ((W) + 1 < 64) { PRODUCE((W) + 1, S) } \
      if ((W) + 4 < 64) { ISSUE((W) + 4, S) } \
    } else { \
      CONSUME(W) \
    } \
  }

  // prologue: producer queues windows 0-2, makes window 0, re-queues into ra
  if (wv != 0) {
    ISSUE(0, ra) ISSUE(1, rb) ISSUE(2, rc)
    PRODUCE(0, ra)
    ISSUE(3, ra)
  }

  int w = 0;
  for (; w + 3 <= nwin; w += 3) {
    BODY(w, rb) BODY(w + 1, rc) BODY(w + 2, ra)
  }
  if (w < nwin) { BODY(w, rb) ++w; }
  if (w < nwin) { BODY(w, rc) ++w; }

  // producer publishes its LSE partial; one more uniform barrier
  if (wv != 0) {
    float a = ((lane & 15) == 15) ? acc : 0.0f;
    a += __shfl_xor(a, 16);
    a += __shfl_xor(a, 32);
    if (lane == 63) lsePart = a;
  }
  barrier_lds();

  if (wv == 0) {
    float ae, ae1;
    if (lab_len >= LL) {            // e = 128
      ae  = i2f(__builtin_amdgcn_readlane(f2i(A2), 63));
      ae1 = i2f(__builtin_amdgcn_readlane(f2i(A1), 63));
    } else if (lab_len >= 1) {      // e = 2*lab_len
      ae  = i2f(__builtin_amdgcn_readlane(f2i(A0), lab_len));
      ae1 = i2f(__builtin_amdgcn_readlane(f2i(A1), lab_len - 1));
    } else {
      ae  = i2f(__builtin_amdgcn_readlane(f2i(A0), 0));
      ae1 = ae;
    }
    const float se = ae + ae1;      // linear-space logaddexp
    float loss = lsePart
               - LN2 * (__builtin_amdgcn_logf(se) - (float)ctot);
    if (lab_len > len) loss = 0.0f; // feasibility mask
    if (lane == 0) atomicAdd(out, loss * (1.0f / 256.0f));
  }
#undef BODY
#undef CONSUME
#undef STEPM
#undef STEPU
#undef RENORM
#undef PRODUCE
#undef PEMIT
#undef ISSUE
}

extern "C" void kernel_launch(void* const* d_in, const int* in_sizes, int n_in,
                              void* d_out, int out_size, void* d_ws, size_t ws_size,
                              hipStream_t stream) {
  (void)in_sizes; (void)n_in; (void)out_size; (void)d_ws; (void)ws_size;
  hipMemsetAsync(d_out, 0, sizeof(float), stream);   // d_out is poisoned 0xAA
  ctc_fused<<<dim3(BB), dim3(128), 0, stream>>>(
      (const int*)d_in[0], (const float*)d_in[1], (const int*)d_in[2], (float*)d_out);
}

// Round 3
// 135.456 us; speedup vs baseline: 1.0932x; 1.0932x over previous
//
#include <hip/hip_runtime.h>

#define BB 256
#define TT 1024
#define VV 64
#define LL 64
#define LOG2E 1.4426950408889634f
#define LN2   0.6931471805599453f

__device__ __forceinline__ int   f2i(float x) { return __float_as_int(x); }
__device__ __forceinline__ float i2f(int x)   { return __int_as_float(x); }

// wave-wide max of non-negative values (0 identity), result broadcast
__device__ __forceinline__ float wave_max63(float x) {
  x = fmaxf(x, i2f(__builtin_amdgcn_update_dpp(0, f2i(x), 0x111, 0xF, 0xF, true)));
  x = fmaxf(x, i2f(__builtin_amdgcn_update_dpp(0, f2i(x), 0x112, 0xF, 0xF, true)));
  x = fmaxf(x, i2f(__builtin_amdgcn_update_dpp(0, f2i(x), 0x114, 0xF, 0xF, true)));
  x = fmaxf(x, i2f(__builtin_amdgcn_update_dpp(0, f2i(x), 0x118, 0xF, 0xF, true)));
  x = fmaxf(x, i2f(__builtin_amdgcn_update_dpp(0, f2i(x), 0x142, 0xF, 0xF, true)));
  x = fmaxf(x, i2f(__builtin_amdgcn_update_dpp(0, f2i(x), 0x143, 0xF, 0xF, true)));
  return i2f(__builtin_amdgcn_readlane(f2i(x), 63));
}

// async 16B/lane global->LDS: LDS dest is wave-uniform base + lane*16,
// global src is per-lane (natural row-major contiguous here).
__device__ __forceinline__ void gload16(const float* g, float* l) {
  __builtin_amdgcn_global_load_lds(
      (const __attribute__((address_space(1))) unsigned int*)g,
      (__attribute__((address_space(3))) unsigned int*)l, 16, 0, 0);
}

// ---------- Fused kernel: block b = batch element b, 5 waves ----------
// R3 change (single variable vs R1): wait discipline. All s_waitcnt are BARE
// inline asm (no "memory" clobber) — a memory-clobber asm is may-load/may-
// store, which forces the compiler to insert vmcnt(0) before it because
// global_load_lds writes LDS; that hidden drain collapsed the 3-deep DMA
// pipeline to depth 0 in R0-R2 (~1 HBM latency paid per window, matching the
// stuck ~2k cy/window). Raw s_barrier + sched_barrier(0) brackets give the
// ordering the clobber used to provide (m201/m218-verified pattern):
//  - pre-barrier sched_barrier: this window's ds_reads can't sink past
//  - post-barrier sched_barrier: next window's ds_reads/GLOAD can't hoist
// No lgkm wait at loop barriers: the only cross-wave LDS writes are DMA,
// ordered by the counted vmcnt. Math identical to R1 (absmax 0.0 there).
extern "C" __global__ void __launch_bounds__(320, 1)
ctc_fused(const int* __restrict__ labels, const float* __restrict__ logits,
          const int* __restrict__ mask, float* __restrict__ out) {
  __shared__ __align__(16) float rawb[4][16][VV];   // 16 KB raw-logit ring
  __shared__ float lsePart[4];
  const int b = blockIdx.x;
  const int tid = threadIdx.x;
  const int lane = tid & 63;
  const int wv = tid >> 6;

  const float* lg = logits + (size_t)b * TT * VV;

  // every wave computes len (redundant, preamble-only)
  int lsum = 0;
  const int* mrow = mask + b * TT;
#pragma unroll
  for (int k = 0; k < TT / 64; ++k) lsum += mrow[lane + (k << 6)];
#pragma unroll
  for (int off = 32; off; off >>= 1) lsum += __shfl_xor(lsum, off);
  int len = __builtin_amdgcn_readfirstlane(lsum);
  len = len < 1 ? 1 : (len > TT ? TT : len);
  const int nwin = (len + 15) >> 4;      // windows actually needed (<= 64)

  // wave-0-only DP state
  int lab = 0, lab_len = 0;
  float sk = 0.0f;
  float A0 = 0.0f, A1 = 0.0f, A2 = 0.0f;
  int ctot = 0;
  if (wv == 0) {
    lab = labels[b * LL + lane] & 63;             // label for state 2*lane+1
    lab_len = (int)__popcll(__ballot(lab != 0));
    const int plab = __builtin_amdgcn_update_dpp(0, lab, 0x138, 0xF, 0xF, false);
    sk = (lab != 0 && lab != plab) ? 1.0f : 0.0f; // allow_skip
    A0 = (lane == 0) ? 1.0f : 0.0f;               // t=0 runs as a normal step
    __builtin_amdgcn_s_setprio(1);                // consumer is critical path
  }

  // producer geometry: wave wv owns window-rows (wv-1)*4 + rg, rg = lane>>4
  const int rg = lane >> 4;
  const int colv = (lane & 15) << 2;
  const int r0 = ((wv - 1) << 2) + rg;
  float acc = 0.0f;

#define GLOAD(WN) gload16(lg + (size_t)(((((WN) << 4) + ((wv - 1) << 2)) << 6) + (lane << 2)), \
                          &rawb[(WN) & 3][(wv - 1) << 2][0])

  // renorm to 2^60 (R9-validated): flush floor ~186 log2 below running max,
  // overflow headroom +67 log2 per 16-step window.
#define RENORM() { \
    const float mxv = wave_max63(fmaxf(fmaxf(A0, A1), A2)); \
    const int eb_ = (f2i(mxv) >> 23) & 255; \
    int kk = (eb_ > 0 && eb_ < 255) ? (187 - eb_) : 0; \
    kk = kk > 126 ? 126 : (kk < -126 ? -126 : kk); \
    ctot += kk; \
    const float sc = i2f((127 + kk) << 23); \
    A0 *= sc; A1 *= sc; A2 *= sc; \
  }

#define STEPU(U) { \
    const float A1p = i2f(__builtin_amdgcn_update_dpp(0, f2i(A1), 0x138, 0xF, 0xF, false)); \
    const float nA0 = c##U * (A0 + A1p); \
    const float nA1 = g##U * fmaf(sk, A1p, A0 + A1); \
    A2 = c##U * (A2 + A1); \
    A0 = nA0; A1 = nA1; \
  }

#define STEPM(U) { \
    const float A1p = i2f(__builtin_amdgcn_update_dpp(0, f2i(A1), 0x138, 0xF, 0xF, false)); \
    const float nA0 = c##U * (A0 + A1p); \
    const float nA1 = g##U * fmaf(sk, A1p, A0 + A1); \
    const float nA2 = c##U * (A2 + A1); \
    const bool act = (tbase + (U)) < len; \
    A0 = act ? nA0 : A0; A1 = act ? nA1 : A1; A2 = act ? nA2 : A2; \
  }

  // prologue: producers queue windows 0,1,2 (depth-4 ring, 3 in flight)
  if (wv != 0) { GLOAD(0); GLOAD(1); GLOAD(2); }

  for (int w = 0; w < nwin; ++w) {
    if (wv != 0) {
      // counted wait: window w's DMA landed; newer loads stay in flight.
      // BARE asm — no clobber, so no compiler-inserted vmcnt(0) drain.
      if (w < 62)       asm volatile("s_waitcnt vmcnt(2)");
      else if (w == 62) asm volatile("s_waitcnt vmcnt(1)");
      else              asm volatile("s_waitcnt vmcnt(0)");
    }
    __builtin_amdgcn_sched_barrier(0);
    __builtin_amdgcn_s_barrier();
    __builtin_amdgcn_sched_barrier(0);
    if (wv != 0) {
      const int wn = w + 3;
      if (wn < 64) GLOAD(wn);            // overwrites slot consumed at w-1
      // ---- row-LSE for window w, own 4 rows ----
      const float4 rv = *(const float4*)&rawb[w & 3][r0][colv];
      const float e0 = __builtin_amdgcn_exp2f(rv.x * LOG2E);
      const float e1 = __builtin_amdgcn_exp2f(rv.y * LOG2E);
      const float e2 = __builtin_amdgcn_exp2f(rv.z * LOG2E);
      const float e3 = __builtin_amdgcn_exp2f(rv.w * LOG2E);
      float s = (e0 + e1) + (e2 + e3);
      // VALU-only 16-lane reduce; result lands in lane 15 of each group
      s += i2f(__builtin_amdgcn_update_dpp(0, f2i(s), 0x111, 0xF, 0xF, true));
      s += i2f(__builtin_amdgcn_update_dpp(0, f2i(s), 0x112, 0xF, 0xF, true));
      s += i2f(__builtin_amdgcn_update_dpp(0, f2i(s), 0x114, 0xF, 0xF, true));
      s += i2f(__builtin_amdgcn_update_dpp(0, f2i(s), 0x118, 0xF, 0xF, true));
      if ((lane & 15) == 15 && (((w << 4) + r0) < len)) acc += __logf(s);
    } else {
      // ---- wave 0: consume window w ----
      const float* rb = &rawb[w & 3][0][0];
      float c0, c1, c2, c3, c4, c5, c6, c7, c8, c9, c10, c11, c12, c13, c14, c15;
      float g0, g1, g2, g3, g4, g5, g6, g7, g8, g9, g10, g11, g12, g13, g14, g15;
#define RD(U) c##U = rb[(U) << 6]; g##U = rb[((U) << 6) + lab];
      RD(0)  RD(1)  RD(2)  RD(3)  RD(4)  RD(5)  RD(6)  RD(7)
      RD(8)  RD(9)  RD(10) RD(11) RD(12) RD(13) RD(14) RD(15)
#undef RD
#define EX(U) c##U = __builtin_amdgcn_exp2f(c##U * LOG2E); \
              g##U = __builtin_amdgcn_exp2f(g##U * LOG2E);
      EX(0)  EX(1)  EX(2)  EX(3)  EX(4)  EX(5)  EX(6)  EX(7)
      EX(8)  EX(9)  EX(10) EX(11) EX(12) EX(13) EX(14) EX(15)
#undef EX
      RENORM()
      const int tbase = w << 4;
      if (tbase + 16 <= len) {   // whole window active: no cndmask on chain
        STEPU(0)  STEPU(1)  STEPU(2)  STEPU(3)  STEPU(4)  STEPU(5)  STEPU(6)  STEPU(7)
        STEPU(8)  STEPU(9)  STEPU(10) STEPU(11) STEPU(12) STEPU(13) STEPU(14) STEPU(15)
      } else {                   // boundary window
        STEPM(0)  STEPM(1)  STEPM(2)  STEPM(3)  STEPM(4)  STEPM(5)  STEPM(6)  STEPM(7)
        STEPM(8)  STEPM(9)  STEPM(10) STEPM(11) STEPM(12) STEPM(13) STEPM(14) STEPM(15)
      }
    }
    __builtin_amdgcn_sched_barrier(0);
  }

  // producers drain stray prefetches (LDS dealloc hazard at wave exit),
  // publish LSE partials; one more barrier before the consumer reads them.
  if (wv != 0) {
    asm volatile("s_waitcnt vmcnt(0)");
    __builtin_amdgcn_sched_barrier(0);
    float a = ((lane & 15) == 15) ? acc : 0.0f;
    a += __shfl_xor(a, 16);
    a += __shfl_xor(a, 32);
    if (lane == 63) lsePart[wv - 1] = a;
    asm volatile("s_waitcnt lgkmcnt(0)");
  }
  __builtin_amdgcn_sched_barrier(0);
  __builtin_amdgcn_s_barrier();
  __builtin_amdgcn_sched_barrier(0);

  if (wv == 0) {
    float ae, ae1;
    if (lab_len >= LL) {            // e = 128
      ae  = i2f(__builtin_amdgcn_readlane(f2i(A2), 63));
      ae1 = i2f(__builtin_amdgcn_readlane(f2i(A1), 63));
    } else if (lab_len >= 1) {      // e = 2*lab_len
      ae  = i2f(__builtin_amdgcn_readlane(f2i(A0), lab_len));
      ae1 = i2f(__builtin_amdgcn_readlane(f2i(A1), lab_len - 1));
    } else {
      ae  = i2f(__builtin_amdgcn_readlane(f2i(A0), 0));
      ae1 = ae;
    }
    const float se = ae + ae1;      // linear-space logaddexp
    float loss = ((lsePart[0] + lsePart[1]) + (lsePart[2] + lsePart[3]))
               - LN2 * (__builtin_amdgcn_logf(se) - (float)ctot);
    if (lab_len > len) loss = 0.0f; // feasibility mask
    if (lane == 0) atomicAdd(out, loss * (1.0f / 256.0f));
  }
#undef STEPM
#undef STEPU
#undef RENORM
#undef GLOAD
}

extern "C" void kernel_launch(void* const* d_in, const int* in_sizes, int n_in,
                              void* d_out, int out_size, void* d_ws, size_t ws_size,
                              hipStream_t stream) {
  (void)in_sizes; (void)n_in; (void)out_size; (void)d_ws; (void)ws_size;
  hipMemsetAsync(d_out, 0, sizeof(float), stream);   // d_out is poisoned 0xAA
  ctc_fused<<<dim3(BB), dim3(320), 0, stream>>>(
      (const int*)d_in[0], (const float*)d_in[1], (const int*)d_in[2], (float*)d_out);
}

// Round 4
// 126.481 us; speedup vs baseline: 1.1708x; 1.0710x over previous
//
#include <hip/hip_runtime.h>

#define BB 256
#define TT 1024
#define VV 64
#define LL 64
#define LOG2E 1.4426950408889634f
#define LN2   0.6931471805599453f

__device__ __forceinline__ int   f2i(float x) { return __float_as_int(x); }
__device__ __forceinline__ float i2f(int x)   { return __int_as_float(x); }

// wave-wide max of non-negative values (0 identity), result broadcast
__device__ __forceinline__ float wave_max63(float x) {
  x = fmaxf(x, i2f(__builtin_amdgcn_update_dpp(0, f2i(x), 0x111, 0xF, 0xF, true)));
  x = fmaxf(x, i2f(__builtin_amdgcn_update_dpp(0, f2i(x), 0x112, 0xF, 0xF, true)));
  x = fmaxf(x, i2f(__builtin_amdgcn_update_dpp(0, f2i(x), 0x114, 0xF, 0xF, true)));
  x = fmaxf(x, i2f(__builtin_amdgcn_update_dpp(0, f2i(x), 0x118, 0xF, 0xF, true)));
  x = fmaxf(x, i2f(__builtin_amdgcn_update_dpp(0, f2i(x), 0x142, 0xF, 0xF, true)));
  x = fmaxf(x, i2f(__builtin_amdgcn_update_dpp(0, f2i(x), 0x143, 0xF, 0xF, true)));
  return i2f(__builtin_amdgcn_readlane(f2i(x), 63));
}

// ---------- R4: fully decoupled kernel, block b = batch element b, 5 waves ----------
// R0-R3 invariant: ~2k cy / 16-row window regardless of producer structure ->
// the cost is the per-window cross-wave coupling (vmcnt wait -> barrier skew ->
// LDS round trip), not the producer. R4 removes it: the DP wave only ever needs
// logits[t][0] and logits[t][lab] -- it loads those 2 values/step itself from
// global (the 64-lane gather spans one 256B row = ~4 cache lines, which the
// LSE waves fetch anyway -> L2 hits). Row-LSE is order-independent and only
// combines at the end, so waves 1-4 stream it fully asynchronously. ZERO
// barriers / LDS traffic in all loops; one s_barrier at the end.
// Math identical to R3 (validated): renorm 2^60, STEPU/STEPM, DPP reduce, and
// identical row->wave->iteration assignment -> bitwise-same lsePart and loss.
extern "C" __global__ void __launch_bounds__(320, 1)
ctc_fused(const int* __restrict__ labels, const float* __restrict__ logits,
          const int* __restrict__ mask, float* __restrict__ out) {
  __shared__ float lsePart[4];
  const int b = blockIdx.x;
  const int tid = threadIdx.x;
  const int lane = tid & 63;
  const int wv = tid >> 6;

  const float* lg = logits + (size_t)b * TT * VV;

  // every wave computes len (redundant, preamble-only)
  int lsum = 0;
  const int* mrow = mask + b * TT;
#pragma unroll
  for (int k = 0; k < TT / 64; ++k) lsum += mrow[lane + (k << 6)];
#pragma unroll
  for (int off = 32; off; off >>= 1) lsum += __shfl_xor(lsum, off);
  int len = __builtin_amdgcn_readfirstlane(lsum);
  len = len < 1 ? 1 : (len > TT ? TT : len);
  const int nwin = (len + 15) >> 4;      // windows actually needed (<= 64)

  // DP state (wave 0 only; declared here for the shared epilogue)
  int lab_len = 0;
  float A0 = 0.0f, A1 = 0.0f, A2 = 0.0f;
  int ctot = 0;

  // renorm to 2^60 (R9-validated): flush floor ~186 log2 below running max,
  // overflow headroom +67 log2 per 16-step window.
#define RENORM() { \
    const float mxv = wave_max63(fmaxf(fmaxf(A0, A1), A2)); \
    const int eb_ = (f2i(mxv) >> 23) & 255; \
    int kk = (eb_ > 0 && eb_ < 255) ? (187 - eb_) : 0; \
    kk = kk > 126 ? 126 : (kk < -126 ? -126 : kk); \
    ctot += kk; \
    const float sc = i2f((127 + kk) << 23); \
    A0 *= sc; A1 *= sc; A2 *= sc; \
  }

#define STEPU(U) { \
    const float A1p = i2f(__builtin_amdgcn_update_dpp(0, f2i(A1), 0x138, 0xF, 0xF, false)); \
    const float nA0 = c##U * (A0 + A1p); \
    const float nA1 = g##U * fmaf(sk, A1p, A0 + A1); \
    A2 = c##U * (A2 + A1); \
    A0 = nA0; A1 = nA1; \
  }

#define STEPM(U) { \
    const float A1p = i2f(__builtin_amdgcn_update_dpp(0, f2i(A1), 0x138, 0xF, 0xF, false)); \
    const float nA0 = c##U * (A0 + A1p); \
    const float nA1 = g##U * fmaf(sk, A1p, A0 + A1); \
    const float nA2 = c##U * (A2 + A1); \
    const bool act = (tbase + (U)) < len; \
    A0 = act ? nA0 : A0; A1 = act ? nA1 : A1; A2 = act ? nA2 : A2; \
  }

  if (wv == 0) {
    // ================= DP wave: self-sufficient, barrier-free =================
    const int lab = labels[b * LL + lane] & 63;     // label for state 2*lane+1
    lab_len = (int)__popcll(__ballot(lab != 0));
    const int plab = __builtin_amdgcn_update_dpp(0, lab, 0x138, 0xF, 0xF, false);
    const float sk = (lab != 0 && lab != plab) ? 1.0f : 0.0f; // allow_skip
    A0 = (lane == 0) ? 1.0f : 0.0f;                 // t=0 runs as a normal step
    __builtin_amdgcn_s_setprio(1);                  // DP wave is the long pole

    const int cu = lane & 15;
    const float* lgg = lg + lab;                    // per-lane gather base
    const float* lgc = lg + (cu << 6);              // lane u<16 -> row u, col 0

    // 3-window-deep static register ring: 17 loads/window, 51 outstanding
    // max (vmcnt cap is 63). Compiler inserts counted vmcnt before first use.
    float qa_c, qb_c, qc_c;
    float qa_g0, qa_g1, qa_g2, qa_g3, qa_g4, qa_g5, qa_g6, qa_g7,
          qa_g8, qa_g9, qa_g10, qa_g11, qa_g12, qa_g13, qa_g14, qa_g15;
    float qb_g0, qb_g1, qb_g2, qb_g3, qb_g4, qb_g5, qb_g6, qb_g7,
          qb_g8, qb_g9, qb_g10, qb_g11, qb_g12, qb_g13, qb_g14, qb_g15;
    float qc_g0, qc_g1, qc_g2, qc_g3, qc_g4, qc_g5, qc_g6, qc_g7,
          qc_g8, qc_g9, qc_g10, qc_g11, qc_g12, qc_g13, qc_g14, qc_g15;

#define CISSUE(WN, S) { \
    const float* pg_ = lgg + ((WN) << 10); \
    S##_g0  = pg_[0];    S##_g1  = pg_[64];   S##_g2  = pg_[128];  S##_g3  = pg_[192]; \
    S##_g4  = pg_[256];  S##_g5  = pg_[320];  S##_g6  = pg_[384];  S##_g7  = pg_[448]; \
    S##_g8  = pg_[512];  S##_g9  = pg_[576];  S##_g10 = pg_[640];  S##_g11 = pg_[704]; \
    S##_g12 = pg_[768];  S##_g13 = pg_[832];  S##_g14 = pg_[896];  S##_g15 = pg_[960]; \
    S##_c = lgc[(WN) << 10]; \
  }

#define CBODY(W, S) { \
    const float cv = __builtin_amdgcn_exp2f(S##_c * LOG2E); \
    const float g0  = __builtin_amdgcn_exp2f(S##_g0  * LOG2E); \
    const float g1  = __builtin_amdgcn_exp2f(S##_g1  * LOG2E); \
    const float g2  = __builtin_amdgcn_exp2f(S##_g2  * LOG2E); \
    const float g3  = __builtin_amdgcn_exp2f(S##_g3  * LOG2E); \
    const float g4  = __builtin_amdgcn_exp2f(S##_g4  * LOG2E); \
    const float g5  = __builtin_amdgcn_exp2f(S##_g5  * LOG2E); \
    const float g6  = __builtin_amdgcn_exp2f(S##_g6  * LOG2E); \
    const float g7  = __builtin_amdgcn_exp2f(S##_g7  * LOG2E); \
    const float g8  = __builtin_amdgcn_exp2f(S##_g8  * LOG2E); \
    const float g9  = __builtin_amdgcn_exp2f(S##_g9  * LOG2E); \
    const float g10 = __builtin_amdgcn_exp2f(S##_g10 * LOG2E); \
    const float g11 = __builtin_amdgcn_exp2f(S##_g11 * LOG2E); \
    const float g12 = __builtin_amdgcn_exp2f(S##_g12 * LOG2E); \
    const float g13 = __builtin_amdgcn_exp2f(S##_g13 * LOG2E); \
    const float g14 = __builtin_amdgcn_exp2f(S##_g14 * LOG2E); \
    const float g15 = __builtin_amdgcn_exp2f(S##_g15 * LOG2E); \
    if ((W) + 3 < 64) { CISSUE((W) + 3, S) }  /* refill: rows <=1023, always in-bounds */ \
    const float c0  = i2f(__builtin_amdgcn_readlane(f2i(cv), 0)); \
    const float c1  = i2f(__builtin_amdgcn_readlane(f2i(cv), 1)); \
    const float c2  = i2f(__builtin_amdgcn_readlane(f2i(cv), 2)); \
    const float c3  = i2f(__builtin_amdgcn_readlane(f2i(cv), 3)); \
    const float c4  = i2f(__builtin_amdgcn_readlane(f2i(cv), 4)); \
    const float c5  = i2f(__builtin_amdgcn_readlane(f2i(cv), 5)); \
    const float c6  = i2f(__builtin_amdgcn_readlane(f2i(cv), 6)); \
    const float c7  = i2f(__builtin_amdgcn_readlane(f2i(cv), 7)); \
    const float c8  = i2f(__builtin_amdgcn_readlane(f2i(cv), 8)); \
    const float c9  = i2f(__builtin_amdgcn_readlane(f2i(cv), 9)); \
    const float c10 = i2f(__builtin_amdgcn_readlane(f2i(cv), 10)); \
    const float c11 = i2f(__builtin_amdgcn_readlane(f2i(cv), 11)); \
    const float c12 = i2f(__builtin_amdgcn_readlane(f2i(cv), 12)); \
    const float c13 = i2f(__builtin_amdgcn_readlane(f2i(cv), 13)); \
    const float c14 = i2f(__builtin_amdgcn_readlane(f2i(cv), 14)); \
    const float c15 = i2f(__builtin_amdgcn_readlane(f2i(cv), 15)); \
    RENORM() \
    const int tbase = (W) << 4; \
    if (tbase + 16 <= len) { \
      STEPU(0)  STEPU(1)  STEPU(2)  STEPU(3)  STEPU(4)  STEPU(5)  STEPU(6)  STEPU(7) \
      STEPU(8)  STEPU(9)  STEPU(10) STEPU(11) STEPU(12) STEPU(13) STEPU(14) STEPU(15) \
    } else { \
      STEPM(0)  STEPM(1)  STEPM(2)  STEPM(3)  STEPM(4)  STEPM(5)  STEPM(6)  STEPM(7) \
      STEPM(8)  STEPM(9)  STEPM(10) STEPM(11) STEPM(12) STEPM(13) STEPM(14) STEPM(15) \
    } \
  }

    CISSUE(0, qa) CISSUE(1, qb) CISSUE(2, qc)
    int w = 0;
    for (; w + 3 <= nwin; w += 3) {
      CBODY(w, qa) CBODY(w + 1, qb) CBODY(w + 2, qc)
    }
    if (w < nwin) { CBODY(w, qa) ++w; }
    if (w < nwin) { CBODY(w, qb) ++w; }
#undef CBODY
#undef CISSUE
  } else {
    // ================= LSE waves: fully async row-LSE streaming =================
    // Same row->(wave,iteration,lane) assignment and fp order as R3's producers:
    // iteration k covers rows k*16 + (wv-1)*4 + prow -> lsePart bitwise identical.
    const int prow = lane >> 4;
    const int pcol = (lane & 15) << 2;
    const float* pb_ = lg + (((((wv - 1) << 2) + prow) << 6) + pcol);
    float acc = 0.0f;
    float4 pa, pb, pc;

#define LISSUE(K, S) { S = *(const float4*)(pb_ + ((K) << 10)); }

#define LBODY(K, S) { \
    const float e0 = __builtin_amdgcn_exp2f(S.x * LOG2E); \
    const float e1 = __builtin_amdgcn_exp2f(S.y * LOG2E); \
    const float e2 = __builtin_amdgcn_exp2f(S.z * LOG2E); \
    const float e3 = __builtin_amdgcn_exp2f(S.w * LOG2E); \
    if ((K) + 3 < 64) { LISSUE((K) + 3, S) } \
    float s = (e0 + e1) + (e2 + e3); \
    s += i2f(__builtin_amdgcn_update_dpp(0, f2i(s), 0x111, 0xF, 0xF, true)); \
    s += i2f(__builtin_amdgcn_update_dpp(0, f2i(s), 0x112, 0xF, 0xF, true)); \
    s += i2f(__builtin_amdgcn_update_dpp(0, f2i(s), 0x114, 0xF, 0xF, true)); \
    s += i2f(__builtin_amdgcn_update_dpp(0, f2i(s), 0x118, 0xF, 0xF, true)); \
    if ((lane & 15) == 15 && ((((K) << 4) + ((wv - 1) << 2) + prow) < len)) acc += __logf(s); \
  }

    LISSUE(0, pa) LISSUE(1, pb) LISSUE(2, pc)
    int k = 0;
    for (; k + 3 <= nwin; k += 3) {
      LBODY(k, pa) LBODY(k + 1, pb) LBODY(k + 2, pc)
    }
    if (k < nwin) { LBODY(k, pa) ++k; }
    if (k < nwin) { LBODY(k, pb) ++k; }
#undef LBODY
#undef LISSUE

    // publish LSE partial (same reduce as R3)
    float a = ((lane & 15) == 15) ? acc : 0.0f;
    a += __shfl_xor(a, 16);
    a += __shfl_xor(a, 32);
    if (lane == 63) lsePart[wv - 1] = a;
    asm volatile("s_waitcnt lgkmcnt(0)");
  }

  // single synchronization point of the whole kernel
  asm volatile("s_waitcnt vmcnt(0)");   // drain stray prefetches (all waves)
  __builtin_amdgcn_s_barrier();

  if (wv == 0) {
    float ae, ae1;
    if (lab_len >= LL) {            // e = 128
      ae  = i2f(__builtin_amdgcn_readlane(f2i(A2), 63));
      ae1 = i2f(__builtin_amdgcn_readlane(f2i(A1), 63));
    } else if (lab_len >= 1) {      // e = 2*lab_len
      ae  = i2f(__builtin_amdgcn_readlane(f2i(A0), lab_len));
      ae1 = i2f(__builtin_amdgcn_readlane(f2i(A1), lab_len - 1));
    } else {
      ae  = i2f(__builtin_amdgcn_readlane(f2i(A0), 0));
      ae1 = ae;
    }
    const float se = ae + ae1;      // linear-space logaddexp
    float loss = ((lsePart[0] + lsePart[1]) + (lsePart[2] + lsePart[3]))
               - LN2 * (__builtin_amdgcn_logf(se) - (float)ctot);
    if (lab_len > len) loss = 0.0f; // feasibility mask
    if (lane == 0) atomicAdd(out, loss * (1.0f / 256.0f));
  }
#undef STEPM
#undef STEPU
#undef RENORM
}

extern "C" void kernel_launch(void* const* d_in, const int* in_sizes, int n_in,
                              void* d_out, int out_size, void* d_ws, size_t ws_size,
                              hipStream_t stream) {
  (void)in_sizes; (void)n_in; (void)out_size; (void)d_ws; (void)ws_size;
  hipMemsetAsync(d_out, 0, sizeof(float), stream);   // d_out is poisoned 0xAA
  ctc_fused<<<dim3(BB), dim3(320), 0, stream>>>(
      (const int*)d_in[0], (const float*)d_in[1], (const int*)d_in[2], (float*)d_out);
}

// Round 5
// 126.033 us; speedup vs baseline: 1.1749x; 1.0036x over previous
//
#include <hip/hip_runtime.h>

#define BB 256
#define TT 1024
#define VV 64
#define LL 64
#define LOG2E 1.4426950408889634f
#define LN2   0.6931471805599453f

__device__ __forceinline__ int   f2i(float x) { return __float_as_int(x); }
__device__ __forceinline__ float i2f(int x)   { return __int_as_float(x); }

// wave-wide max of non-negative values (0 identity), result broadcast
__device__ __forceinline__ float wave_max63(float x) {
  x = fmaxf(x, i2f(__builtin_amdgcn_update_dpp(0, f2i(x), 0x111, 0xF, 0xF, true)));
  x = fmaxf(x, i2f(__builtin_amdgcn_update_dpp(0, f2i(x), 0x112, 0xF, 0xF, true)));
  x = fmaxf(x, i2f(__builtin_amdgcn_update_dpp(0, f2i(x), 0x114, 0xF, 0xF, true)));
  x = fmaxf(x, i2f(__builtin_amdgcn_update_dpp(0, f2i(x), 0x118, 0xF, 0xF, true)));
  x = fmaxf(x, i2f(__builtin_amdgcn_update_dpp(0, f2i(x), 0x142, 0xF, 0xF, true)));
  x = fmaxf(x, i2f(__builtin_amdgcn_update_dpp(0, f2i(x), 0x143, 0xF, 0xF, true)));
  return i2f(__builtin_amdgcn_readlane(f2i(x), 63));
}

// ---------- R5: deep LDS ring + rare barriers, block b = batch element b ----------
// R4 showed the DP wave solo at ~107 cy/step; the overhead on its critical path
// was its OWN 17 exps (quarter-rate trans), 16 readlanes, and global-gather
// vmcnt waits. R5 moves all of that to the producer waves (8x slack): they exp
// once and write emission rows + packed c-row into a 16-window (64KB) LDS ring.
// Sync is ONE __syncthreads per 8-window half (~9 barriers total vs 64 in
// R0-R3 -- per-window barriers were the earlier killer). Consumer window body:
// 16 independent ds_read_b32 g-gathers (<=2-way bank aliasing = free; duplicate
// labels broadcast) + 4 uniform b128 c-broadcasts + renorm + 16 steps. Zero
// exps / readlanes / vmem on the serial wave. Producers keep an 8-deep STATIC
// float4 register ring (all indices compile-time); __syncthreads' vmcnt drain
// costs only producer slack. Math bit-identical to R4 (same exp op, DPP trees,
// renorm 2^60, epilogue).
extern "C" __global__ void __launch_bounds__(320, 1)
ctc_fused(const int* __restrict__ labels, const float* __restrict__ logits,
          const int* __restrict__ mask, float* __restrict__ out) {
  __shared__ __align__(16) float ebuf[16][16][VV];  // 64 KB: 16-window emission ring
  __shared__ __align__(16) float cbuf[16][16];      // packed blank emissions per window
  __shared__ float lsePart[4];
  const int b = blockIdx.x;
  const int tid = threadIdx.x;
  const int lane = tid & 63;
  const int wv = tid >> 6;

  const float* lg = logits + (size_t)b * TT * VV;

  // every wave computes len (redundant, preamble-only)
  int lsum = 0;
  const int* mrow = mask + b * TT;
#pragma unroll
  for (int k = 0; k < TT / 64; ++k) lsum += mrow[lane + (k << 6)];
#pragma unroll
  for (int off = 32; off; off >>= 1) lsum += __shfl_xor(lsum, off);
  int len = __builtin_amdgcn_readfirstlane(lsum);
  len = len < 1 ? 1 : (len > TT ? TT : len);
  const int nwin = (len + 15) >> 4;      // windows actually needed (<= 64)
  const int nI = (nwin + 7) >> 3;        // 8-window intervals (>= 2 for len >= 129)

  // DP state (wave 0 only; top-level for the shared epilogue)
  int lab = 0, lab_len = 0;
  float sk = 0.0f;
  float A0 = 0.0f, A1 = 0.0f, A2 = 0.0f;
  int ctot = 0;

  // producer state (waves 1-4; top-level so it survives the shared k-loop)
  const int rg = lane >> 4;              // row-in-window-group 0..3
  const int colv = (lane & 15) << 2;     // vocab base 0..60
  const int prow16 = ((wv - 1) << 2) + rg;   // row 0..15 within a window (wv>=1)
  const float* pg = lg;                  // set properly in producer init
  float acc = 0.0f;
  float4 r0{0,0,0,0}, r1{0,0,0,0}, r2{0,0,0,0}, r3{0,0,0,0},
         r4{0,0,0,0}, r5{0,0,0,0}, r6{0,0,0,0}, r7{0,0,0,0};

#define PISSUE(W, RJ) { RJ = *(const float4*)(pg + ((size_t)(W) << 10)); }

// produce window W from ring reg RJ (exp + LDS write + row-LSE), then refill
// RJ with window W+8's load. All guards wave-uniform; all reg indices static.
#define PPROD(W, RJ) { \
    if ((W) < 64) { \
      const float e0 = __builtin_amdgcn_exp2f(RJ.x * LOG2E); \
      const float e1 = __builtin_amdgcn_exp2f(RJ.y * LOG2E); \
      const float e2 = __builtin_amdgcn_exp2f(RJ.z * LOG2E); \
      const float e3 = __builtin_amdgcn_exp2f(RJ.w * LOG2E); \
      float4 ev; ev.x = e0; ev.y = e1; ev.z = e2; ev.w = e3; \
      *(float4*)&ebuf[(W) & 15][prow16][colv] = ev; \
      if ((lane & 15) == 0) cbuf[(W) & 15][prow16] = e0; \
      float s = (e0 + e1) + (e2 + e3); \
      s += i2f(__builtin_amdgcn_update_dpp(0, f2i(s), 0x111, 0xF, 0xF, true)); \
      s += i2f(__builtin_amdgcn_update_dpp(0, f2i(s), 0x112, 0xF, 0xF, true)); \
      s += i2f(__builtin_amdgcn_update_dpp(0, f2i(s), 0x114, 0xF, 0xF, true)); \
      s += i2f(__builtin_amdgcn_update_dpp(0, f2i(s), 0x118, 0xF, 0xF, true)); \
      if ((lane & 15) == 15 && ((((W) << 4) + prow16) < len)) acc += __logf(s); \
      if ((W) + 8 < 64) { PISSUE((W) + 8, RJ) } \
    } \
  }

  // renorm to 2^60 (R9-validated): flush floor ~186 log2 below running max,
  // overflow headroom +67 log2 per 16-step window.
#define RENORM() { \
    const float mxv = wave_max63(fmaxf(fmaxf(A0, A1), A2)); \
    const int eb_ = (f2i(mxv) >> 23) & 255; \
    int kk = (eb_ > 0 && eb_ < 255) ? (187 - eb_) : 0; \
    kk = kk > 126 ? 126 : (kk < -126 ? -126 : kk); \
    ctot += kk; \
    const float sc = i2f((127 + kk) << 23); \
    A0 *= sc; A1 *= sc; A2 *= sc; \
  }

#define STEPU(U) { \
    const float A1p = i2f(__builtin_amdgcn_update_dpp(0, f2i(A1), 0x138, 0xF, 0xF, false)); \
    const float nA0 = c##U * (A0 + A1p); \
    const float nA1 = g##U * fmaf(sk, A1p, A0 + A1); \
    A2 = c##U * (A2 + A1); \
    A0 = nA0; A1 = nA1; \
  }

#define STEPM(U) { \
    const float A1p = i2f(__builtin_amdgcn_update_dpp(0, f2i(A1), 0x138, 0xF, 0xF, false)); \
    const float nA0 = c##U * (A0 + A1p); \
    const float nA1 = g##U * fmaf(sk, A1p, A0 + A1); \
    const float nA2 = c##U * (A2 + A1); \
    const bool act = (tbase + (U)) < len; \
    A0 = act ? nA0 : A0; A1 = act ? nA1 : A1; A2 = act ? nA2 : A2; \
  }

// consumer: one window entirely from LDS (issue reads early, use late)
#define CWIN(W) { \
    const int slot_ = (W) & 15; \
    const float* eb = &ebuf[slot_][0][0]; \
    float g0,g1,g2,g3,g4,g5,g6,g7,g8,g9,g10,g11,g12,g13,g14,g15; \
    g0  = eb[(0 << 6)  + lab]; g1  = eb[(1 << 6)  + lab]; \
    g2  = eb[(2 << 6)  + lab]; g3  = eb[(3 << 6)  + lab]; \
    g4  = eb[(4 << 6)  + lab]; g5  = eb[(5 << 6)  + lab]; \
    g6  = eb[(6 << 6)  + lab]; g7  = eb[(7 << 6)  + lab]; \
    g8  = eb[(8 << 6)  + lab]; g9  = eb[(9 << 6)  + lab]; \
    g10 = eb[(10 << 6) + lab]; g11 = eb[(11 << 6) + lab]; \
    g12 = eb[(12 << 6) + lab]; g13 = eb[(13 << 6) + lab]; \
    g14 = eb[(14 << 6) + lab]; g15 = eb[(15 << 6) + lab]; \
    const float4* cp = (const float4*)&cbuf[slot_][0]; \
    const float4 cva = cp[0], cvb = cp[1], cvc = cp[2], cvd = cp[3]; \
    const float c0 = cva.x,  c1 = cva.y,  c2 = cva.z,  c3 = cva.w; \
    const float c4 = cvb.x,  c5 = cvb.y,  c6 = cvb.z,  c7 = cvb.w; \
    const float c8 = cvc.x,  c9 = cvc.y,  c10 = cvc.z, c11 = cvc.w; \
    const float c12 = cvd.x, c13 = cvd.y, c14 = cvd.z, c15 = cvd.w; \
    RENORM() \
    const int tbase = (W) << 4; \
    if (tbase + 16 <= len) { \
      STEPU(0)  STEPU(1)  STEPU(2)  STEPU(3)  STEPU(4)  STEPU(5)  STEPU(6)  STEPU(7) \
      STEPU(8)  STEPU(9)  STEPU(10) STEPU(11) STEPU(12) STEPU(13) STEPU(14) STEPU(15) \
    } else { \
      STEPM(0)  STEPM(1)  STEPM(2)  STEPM(3)  STEPM(4)  STEPM(5)  STEPM(6)  STEPM(7) \
      STEPM(8)  STEPM(9)  STEPM(10) STEPM(11) STEPM(12) STEPM(13) STEPM(14) STEPM(15) \
    } \
  }

  if (wv == 0) {
    // ---- DP wave init ----
    lab = labels[b * LL + lane] & 63;               // label for state 2*lane+1
    lab_len = (int)__popcll(__ballot(lab != 0));
    const int plab = __builtin_amdgcn_update_dpp(0, lab, 0x138, 0xF, 0xF, false);
    sk = (lab != 0 && lab != plab) ? 1.0f : 0.0f;   // allow_skip
    A0 = (lane == 0) ? 1.0f : 0.0f;                 // t=0 runs as a normal step
    __builtin_amdgcn_s_setprio(1);                  // consumer is the long pole
  } else {
    // ---- producer init + prologue: fill windows 0..7 (ring loads 8..15) ----
    pg = lg + ((size_t)prow16 << 6) + colv;
    PISSUE(0, r0) PISSUE(1, r1) PISSUE(2, r2) PISSUE(3, r3)
    PISSUE(4, r4) PISSUE(5, r5) PISSUE(6, r6) PISSUE(7, r7)
    PPROD(0, r0) PPROD(1, r1) PPROD(2, r2) PPROD(3, r3)
    PPROD(4, r4) PPROD(5, r5) PPROD(6, r6) PPROD(7, r7)
  }
  __syncthreads();

  for (int k = 0; k < nI; ++k) {
    if (wv == 0) {
      const int w0 = k << 3;
      const int wend = (w0 + 8 < nwin) ? (w0 + 8) : nwin;
      for (int w = w0; w < wend; ++w) { CWIN(w) }
    } else {
      const int W0 = (k << 3) + 8;     // produce next half while consumer eats
      PPROD(W0 + 0, r0) PPROD(W0 + 1, r1) PPROD(W0 + 2, r2) PPROD(W0 + 3, r3)
      PPROD(W0 + 4, r4) PPROD(W0 + 5, r5) PPROD(W0 + 6, r6) PPROD(W0 + 7, r7)
    }
    __syncthreads();   // also drains producers' vmem (their slack absorbs it)
  }

  // producers publish LSE partials; one more barrier before the epilogue
  if (wv != 0) {
    float a = ((lane & 15) == 15) ? acc : 0.0f;
    a += __shfl_xor(a, 16);
    a += __shfl_xor(a, 32);
    if (lane == 63) lsePart[wv - 1] = a;
  }
  __syncthreads();

  if (wv == 0) {
    float ae, ae1;
    if (lab_len >= LL) {            // e = 128
      ae  = i2f(__builtin_amdgcn_readlane(f2i(A2), 63));
      ae1 = i2f(__builtin_amdgcn_readlane(f2i(A1), 63));
    } else if (lab_len >= 1) {      // e = 2*lab_len
      ae  = i2f(__builtin_amdgcn_readlane(f2i(A0), lab_len));
      ae1 = i2f(__builtin_amdgcn_readlane(f2i(A1), lab_len - 1));
    } else {
      ae  = i2f(__builtin_amdgcn_readlane(f2i(A0), 0));
      ae1 = ae;
    }
    const float se = ae + ae1;      // linear-space logaddexp
    float loss = ((lsePart[0] + lsePart[1]) + (lsePart[2] + lsePart[3]))
               - LN2 * (__builtin_amdgcn_logf(se) - (float)ctot);
    if (lab_len > len) loss = 0.0f; // feasibility mask
    if (lane == 0) atomicAdd(out, loss * (1.0f / 256.0f));
  }
#undef CWIN
#undef STEPM
#undef STEPU
#undef RENORM
#undef PPROD
#undef PISSUE
}

extern "C" void kernel_launch(void* const* d_in, const int* in_sizes, int n_in,
                              void* d_out, int out_size, void* d_ws, size_t ws_size,
                              hipStream_t stream) {
  (void)in_sizes; (void)n_in; (void)out_size; (void)d_ws; (void)ws_size;
  hipMemsetAsync(d_out, 0, sizeof(float), stream);   // d_out is poisoned 0xAA
  ctc_fused<<<dim3(BB), dim3(320), 0, stream>>>(
      (const int*)d_in[0], (const float*)d_in[1], (const int*)d_in[2], (float*)d_out);
}

// Round 7
// 119.612 us; speedup vs baseline: 1.2380x; 1.0537x over previous
//
#include <hip/hip_runtime.h>

#define BB 256
#define TT 1024
#define VV 64
#define LL 64
#define LOG2E 1.4426950408889634f
#define LN2   0.6931471805599453f

__device__ __forceinline__ int   f2i(float x) { return __float_as_int(x); }
__device__ __forceinline__ float i2f(int x)   { return __int_as_float(x); }

// wave-wide max of non-negative values (0 identity), result broadcast
__device__ __forceinline__ float wave_max63(float x) {
  x = fmaxf(x, i2f(__builtin_amdgcn_update_dpp(0, f2i(x), 0x111, 0xF, 0xF, true)));
  x = fmaxf(x, i2f(__builtin_amdgcn_update_dpp(0, f2i(x), 0x112, 0xF, 0xF, true)));
  x = fmaxf(x, i2f(__builtin_amdgcn_update_dpp(0, f2i(x), 0x114, 0xF, 0xF, true)));
  x = fmaxf(x, i2f(__builtin_amdgcn_update_dpp(0, f2i(x), 0x118, 0xF, 0xF, true)));
  x = fmaxf(x, i2f(__builtin_amdgcn_update_dpp(0, f2i(x), 0x142, 0xF, 0xF, true)));
  x = fmaxf(x, i2f(__builtin_amdgcn_update_dpp(0, f2i(x), 0x143, 0xF, 0xF, true)));
  return i2f(__builtin_amdgcn_readlane(f2i(x), 63));
}

// ---------- R7: R6 fwd/bwd split + final rescale to 2^45 before the combine ----------
// R6's NaN: A,G each renorm to 2^60/window then grow ~2^20-40 -> A*G ~ 2^140+
// = inf at the combine; a disjoint-support block gives p=0 -> +inf loss; one
// -inf block + one +inf block in the same atomicAdd = NaN. Fix: one extra
// renorm (target 2^45, kk=172-eb, tracked in ctot) at the END of each DP wave
// -- product terms <= 2^90, sum <= 2^97, flush floor ~216 log2 below max term
// (more margin than the validated 2^60/186 in-loop discipline). p clamped at
// 1e-37 so a pathological block cannot poison the batch mean with +/-inf.
// Everything else identical to R6 (structure) / R4 (feeding, validated).
extern "C" __global__ void __launch_bounds__(384, 1)
ctc_fused(const int* __restrict__ labels, const float* __restrict__ logits,
          const int* __restrict__ mask, float* __restrict__ out) {
  __shared__ float lsePart[4];
  __shared__ float sG0v[64], sG1v[64];
  __shared__ float sG2s;
  __shared__ int   sCtB;
  const int b = blockIdx.x;
  const int tid = threadIdx.x;
  const int lane = tid & 63;
  const int wv = tid >> 6;

  const float* lg = logits + (size_t)b * TT * VV;

  // every wave computes len (redundant, preamble-only)
  int lsum = 0;
  const int* mrow = mask + b * TT;
#pragma unroll
  for (int k = 0; k < TT / 64; ++k) lsum += mrow[lane + (k << 6)];
#pragma unroll
  for (int off = 32; off; off >>= 1) lsum += __shfl_xor(lsum, off);
  int len = __builtin_amdgcn_readfirstlane(lsum);
  len = len < 1 ? 1 : (len > TT ? TT : len);
  const int nwin = (len + 15) >> 4;          // LSE windows (all rows < len)
  int mid = len >> 1; mid = mid < 1 ? 1 : mid;
  const int nwF = (mid + 15) >> 4;           // forward windows: rows [0, mid)
  const int nwB = (len - mid + 15) >> 4;     // backward windows: rows [len-1, mid]

  // forward state (wave 0 only; top-level for the epilogue)
  int lab_len = 0;
  float A0 = 0.0f, A1 = 0.0f, A2 = 0.0f;
  int ctotA = 0;

#define RENORM3(X, Y, Z, CT) { \
    const float mxv = wave_max63(fmaxf(fmaxf(X, Y), Z)); \
    const int eb_ = (f2i(mxv) >> 23) & 255; \
    int kk = (eb_ > 0 && eb_ < 255) ? (187 - eb_) : 0; \
    kk = kk > 126 ? 126 : (kk < -126 ? -126 : kk); \
    CT += kk; \
    const float sc = i2f((127 + kk) << 23); \
    X *= sc; Y *= sc; Z *= sc; \
  }

  // final rescale to 2^45: keeps the cross-wave product within fp32 range
#define RESCALE45(X, Y, Z, CT) { \
    const float mxv = wave_max63(fmaxf(fmaxf(X, Y), Z)); \
    const int eb_ = (f2i(mxv) >> 23) & 255; \
    int kk = (eb_ > 0 && eb_ < 255) ? (172 - eb_) : 0; \
    kk = kk > 126 ? 126 : (kk < -126 ? -126 : kk); \
    CT += kk; \
    const float sc = i2f((127 + kk) << 23); \
    X *= sc; Y *= sc; Z *= sc; \
  }

  if (wv == 0) {
    // ================= forward DP wave: rows [0, mid) =================
    const int lab = labels[b * LL + lane] & 63;   // label for state 2*lane+1
    lab_len = (int)__popcll(__ballot(lab != 0));
    const int plab = __builtin_amdgcn_update_dpp(0, lab, 0x138, 0xF, 0xF, false);
    const float sk = (lab != 0 && lab != plab) ? 1.0f : 0.0f; // allow_skip
    A0 = (lane == 0) ? 1.0f : 0.0f;               // t=0 runs as a normal step
    __builtin_amdgcn_s_setprio(1);

    const int cu = lane & 15;
    const float* lgg = lg + lab;                  // per-lane gather base
    const float* lgc = lg + (cu << 6);            // lane u<16 -> row u, col 0

    float qa_c, qb_c, qc_c;
    float qa_g0, qa_g1, qa_g2, qa_g3, qa_g4, qa_g5, qa_g6, qa_g7,
          qa_g8, qa_g9, qa_g10, qa_g11, qa_g12, qa_g13, qa_g14, qa_g15;
    float qb_g0, qb_g1, qb_g2, qb_g3, qb_g4, qb_g5, qb_g6, qb_g7,
          qb_g8, qb_g9, qb_g10, qb_g11, qb_g12, qb_g13, qb_g14, qb_g15;
    float qc_g0, qc_g1, qc_g2, qc_g3, qc_g4, qc_g5, qc_g6, qc_g7,
          qc_g8, qc_g9, qc_g10, qc_g11, qc_g12, qc_g13, qc_g14, qc_g15;

#define FISSUE(WN, S) { \
    const float* pg_ = lgg + ((WN) << 10); \
    S##_g0  = pg_[0];    S##_g1  = pg_[64];   S##_g2  = pg_[128];  S##_g3  = pg_[192]; \
    S##_g4  = pg_[256];  S##_g5  = pg_[320];  S##_g6  = pg_[384];  S##_g7  = pg_[448]; \
    S##_g8  = pg_[512];  S##_g9  = pg_[576];  S##_g10 = pg_[640];  S##_g11 = pg_[704]; \
    S##_g12 = pg_[768];  S##_g13 = pg_[832];  S##_g14 = pg_[896];  S##_g15 = pg_[960]; \
    S##_c = lgc[(WN) << 10]; \
  }

#define FSTEPU(U) { \
    const float A1p = i2f(__builtin_amdgcn_update_dpp(0, f2i(A1), 0x138, 0xF, 0xF, false)); \
    const float nA0 = c##U * (A0 + A1p); \
    const float nA1 = g##U * fmaf(sk, A1p, A0 + A1); \
    A2 = c##U * (A2 + A1); \
    A0 = nA0; A1 = nA1; \
  }

#define FSTEPM(U) { \
    const float A1p = i2f(__builtin_amdgcn_update_dpp(0, f2i(A1), 0x138, 0xF, 0xF, false)); \
    const float nA0 = c##U * (A0 + A1p); \
    const float nA1 = g##U * fmaf(sk, A1p, A0 + A1); \
    const float nA2 = c##U * (A2 + A1); \
    const bool act = (tbase + (U)) < mid; \
    A0 = act ? nA0 : A0; A1 = act ? nA1 : A1; A2 = act ? nA2 : A2; \
  }

#define FBODY(W, S) { \
    const float cv = __builtin_amdgcn_exp2f(S##_c * LOG2E); \
    const float g0  = __builtin_amdgcn_exp2f(S##_g0  * LOG2E); \
    const float g1  = __builtin_amdgcn_exp2f(S##_g1  * LOG2E); \
    const float g2  = __builtin_amdgcn_exp2f(S##_g2  * LOG2E); \
    const float g3  = __builtin_amdgcn_exp2f(S##_g3  * LOG2E); \
    const float g4  = __builtin_amdgcn_exp2f(S##_g4  * LOG2E); \
    const float g5  = __builtin_amdgcn_exp2f(S##_g5  * LOG2E); \
    const float g6  = __builtin_amdgcn_exp2f(S##_g6  * LOG2E); \
    const float g7  = __builtin_amdgcn_exp2f(S##_g7  * LOG2E); \
    const float g8  = __builtin_amdgcn_exp2f(S##_g8  * LOG2E); \
    const float g9  = __builtin_amdgcn_exp2f(S##_g9  * LOG2E); \
    const float g10 = __builtin_amdgcn_exp2f(S##_g10 * LOG2E); \
    const float g11 = __builtin_amdgcn_exp2f(S##_g11 * LOG2E); \
    const float g12 = __builtin_amdgcn_exp2f(S##_g12 * LOG2E); \
    const float g13 = __builtin_amdgcn_exp2f(S##_g13 * LOG2E); \
    const float g14 = __builtin_amdgcn_exp2f(S##_g14 * LOG2E); \
    const float g15 = __builtin_amdgcn_exp2f(S##_g15 * LOG2E); \
    if ((W) + 3 < 64) { FISSUE((W) + 3, S) } \
    const float c0  = i2f(__builtin_amdgcn_readlane(f2i(cv), 0)); \
    const float c1  = i2f(__builtin_amdgcn_readlane(f2i(cv), 1)); \
    const float c2  = i2f(__builtin_amdgcn_readlane(f2i(cv), 2)); \
    const float c3  = i2f(__builtin_amdgcn_readlane(f2i(cv), 3)); \
    const float c4  = i2f(__builtin_amdgcn_readlane(f2i(cv), 4)); \
    const float c5  = i2f(__builtin_amdgcn_readlane(f2i(cv), 5)); \
    const float c6  = i2f(__builtin_amdgcn_readlane(f2i(cv), 6)); \
    const float c7  = i2f(__builtin_amdgcn_readlane(f2i(cv), 7)); \
    const float c8  = i2f(__builtin_amdgcn_readlane(f2i(cv), 8)); \
    const float c9  = i2f(__builtin_amdgcn_readlane(f2i(cv), 9)); \
    const float c10 = i2f(__builtin_amdgcn_readlane(f2i(cv), 10)); \
    const float c11 = i2f(__builtin_amdgcn_readlane(f2i(cv), 11)); \
    const float c12 = i2f(__builtin_amdgcn_readlane(f2i(cv), 12)); \
    const float c13 = i2f(__builtin_amdgcn_readlane(f2i(cv), 13)); \
    const float c14 = i2f(__builtin_amdgcn_readlane(f2i(cv), 14)); \
    const float c15 = i2f(__builtin_amdgcn_readlane(f2i(cv), 15)); \
    RENORM3(A0, A1, A2, ctotA) \
    const int tbase = (W) << 4; \
    if (tbase + 16 <= mid) { \
      FSTEPU(0)  FSTEPU(1)  FSTEPU(2)  FSTEPU(3)  FSTEPU(4)  FSTEPU(5)  FSTEPU(6)  FSTEPU(7) \
      FSTEPU(8)  FSTEPU(9)  FSTEPU(10) FSTEPU(11) FSTEPU(12) FSTEPU(13) FSTEPU(14) FSTEPU(15) \
    } else { \
      FSTEPM(0)  FSTEPM(1)  FSTEPM(2)  FSTEPM(3)  FSTEPM(4)  FSTEPM(5)  FSTEPM(6)  FSTEPM(7) \
      FSTEPM(8)  FSTEPM(9)  FSTEPM(10) FSTEPM(11) FSTEPM(12) FSTEPM(13) FSTEPM(14) FSTEPM(15) \
    } \
  }

    FISSUE(0, qa) FISSUE(1, qb) FISSUE(2, qc)
    int w = 0;
    for (; w + 3 <= nwF; w += 3) {
      FBODY(w, qa) FBODY(w + 1, qb) FBODY(w + 2, qc)
    }
    if (w < nwF) { FBODY(w, qa) ++w; }
    if (w < nwF) { FBODY(w, qb) ++w; }
#undef FBODY
#undef FSTEPM
#undef FSTEPU
#undef FISSUE
    RESCALE45(A0, A1, A2, ctotA)

  } else if (wv == 1) {
    // ================= backward (suffix) DP wave: rows [len-1, mid] =================
    const int lab = labels[b * LL + lane] & 63;
    const int ll = (int)__popcll(__ballot(lab != 0));
    const int plab = __builtin_amdgcn_update_dpp(0, lab, 0x138, 0xF, 0xF, false);
    const float sk = (lab != 0 && lab != plab) ? 1.0f : 0.0f;
    const float skp = i2f(__builtin_amdgcn_update_dpp(0, f2i(sk), 0x130, 0xF, 0xF, false)); // sk[l+1]
    const bool is63 = (lane == 63);
    __builtin_amdgcn_s_setprio(1);

    // gamma seeds at t = len: [s==e] + [s==max(e-1,0)], e = 2*ll
    float G0 = 0.0f, G1 = 0.0f, G2 = 0.0f;
    if (ll == 0)            { G0 = (lane == 0) ? 2.0f : 0.0f; }
    else if (ll >= LL)      { G2 = 1.0f; G1 = is63 ? 1.0f : 0.0f; }
    else {
      G0 = (lane == ll) ? 1.0f : 0.0f;
      G1 = (lane == ll - 1) ? 1.0f : 0.0f;
    }
    int ctotB = 0;

    const int cu = lane & 15;
    const float* lgg = lg + lab;

    float ra_c, rb_c, rc_c;
    float ra_g0, ra_g1, ra_g2, ra_g3, ra_g4, ra_g5, ra_g6, ra_g7,
          ra_g8, ra_g9, ra_g10, ra_g11, ra_g12, ra_g13, ra_g14, ra_g15;
    float rb_g0, rb_g1, rb_g2, rb_g3, rb_g4, rb_g5, rb_g6, rb_g7,
          rb_g8, rb_g9, rb_g10, rb_g11, rb_g12, rb_g13, rb_g14, rb_g15;
    float rc_g0, rc_g1, rc_g2, rc_g3, rc_g4, rc_g5, rc_g6, rc_g7,
          rc_g8, rc_g9, rc_g10, rc_g11, rc_g12, rc_g13, rc_g14, rc_g15;

#define BLD(RW) ( (RW) < 0 ? 0 : (RW) )
#define BISSUE(J, S) { \
    const int br_ = len - 1 - ((J) << 4); \
    S##_g0  = lgg[BLD(br_ - 0)  << 6]; S##_g1  = lgg[BLD(br_ - 1)  << 6]; \
    S##_g2  = lgg[BLD(br_ - 2)  << 6]; S##_g3  = lgg[BLD(br_ - 3)  << 6]; \
    S##_g4  = lgg[BLD(br_ - 4)  << 6]; S##_g5  = lgg[BLD(br_ - 5)  << 6]; \
    S##_g6  = lgg[BLD(br_ - 6)  << 6]; S##_g7  = lgg[BLD(br_ - 7)  << 6]; \
    S##_g8  = lgg[BLD(br_ - 8)  << 6]; S##_g9  = lgg[BLD(br_ - 9)  << 6]; \
    S##_g10 = lgg[BLD(br_ - 10) << 6]; S##_g11 = lgg[BLD(br_ - 11) << 6]; \
    S##_g12 = lgg[BLD(br_ - 12) << 6]; S##_g13 = lgg[BLD(br_ - 13) << 6]; \
    S##_g14 = lgg[BLD(br_ - 14) << 6]; S##_g15 = lgg[BLD(br_ - 15) << 6]; \
    S##_c = lg[BLD(br_ - cu) << 6]; \
  }

#define BSTEPU(U) { \
    const float V_ = i2f(__builtin_amdgcn_update_dpp(0, f2i(G1), 0x130, 0xF, 0xF, false)); \
    float U_ = i2f(__builtin_amdgcn_update_dpp(0, f2i(G0), 0x130, 0xF, 0xF, false)); \
    U_ = is63 ? G2 : U_; \
    const float nG0 = fmaf(cB##U, G0, gB##U * G1); \
    const float nG1 = fmaf(gB##U, G1, fmaf(cB##U, U_, hB##U * V_)); \
    G2 = cB##U * G2; \
    G0 = nG0; G1 = nG1; \
  }

#define BSTEPM(U) { \
    const float V_ = i2f(__builtin_amdgcn_update_dpp(0, f2i(G1), 0x130, 0xF, 0xF, false)); \
    float U_ = i2f(__builtin_amdgcn_update_dpp(0, f2i(G0), 0x130, 0xF, 0xF, false)); \
    U_ = is63 ? G2 : U_; \
    const float nG0 = fmaf(cB##U, G0, gB##U * G1); \
    const float nG1 = fmaf(gB##U, G1, fmaf(cB##U, U_, hB##U * V_)); \
    const float nG2 = cB##U * G2; \
    const bool act = (brow0 - (U)) >= mid; \
    G0 = act ? nG0 : G0; G1 = act ? nG1 : G1; G2 = act ? nG2 : G2; \
  }

#define BPREP(U, S) \
    const float gB##U = __builtin_amdgcn_exp2f(S##_g##U * LOG2E); \
    const float hB##U = skp * i2f(__builtin_amdgcn_update_dpp(0, f2i(gB##U), 0x130, 0xF, 0xF, false));

#define BBODY(J, S) { \
    const int brow0 = len - 1 - ((J) << 4); \
    const float cv = __builtin_amdgcn_exp2f(S##_c * LOG2E); \
    BPREP(0, S)  BPREP(1, S)  BPREP(2, S)  BPREP(3, S) \
    BPREP(4, S)  BPREP(5, S)  BPREP(6, S)  BPREP(7, S) \
    BPREP(8, S)  BPREP(9, S)  BPREP(10, S) BPREP(11, S) \
    BPREP(12, S) BPREP(13, S) BPREP(14, S) BPREP(15, S) \
    if ((J) + 3 < 64) { BISSUE((J) + 3, S) } \
    const float cB0  = i2f(__builtin_amdgcn_readlane(f2i(cv), 0)); \
    const float cB1  = i2f(__builtin_amdgcn_readlane(f2i(cv), 1)); \
    const float cB2  = i2f(__builtin_amdgcn_readlane(f2i(cv), 2)); \
    const float cB3  = i2f(__builtin_amdgcn_readlane(f2i(cv), 3)); \
    const float cB4  = i2f(__builtin_amdgcn_readlane(f2i(cv), 4)); \
    const float cB5  = i2f(__builtin_amdgcn_readlane(f2i(cv), 5)); \
    const float cB6  = i2f(__builtin_amdgcn_readlane(f2i(cv), 6)); \
    const float cB7  = i2f(__builtin_amdgcn_readlane(f2i(cv), 7)); \
    const float cB8  = i2f(__builtin_amdgcn_readlane(f2i(cv), 8)); \
    const float cB9  = i2f(__builtin_amdgcn_readlane(f2i(cv), 9)); \
    const float cB10 = i2f(__builtin_amdgcn_readlane(f2i(cv), 10)); \
    const float cB11 = i2f(__builtin_amdgcn_readlane(f2i(cv), 11)); \
    const float cB12 = i2f(__builtin_amdgcn_readlane(f2i(cv), 12)); \
    const float cB13 = i2f(__builtin_amdgcn_readlane(f2i(cv), 13)); \
    const float cB14 = i2f(__builtin_amdgcn_readlane(f2i(cv), 14)); \
    const float cB15 = i2f(__builtin_amdgcn_readlane(f2i(cv), 15)); \
    RENORM3(G0, G1, G2, ctotB) \
    if (brow0 - 15 >= mid) { \
      BSTEPU(0)  BSTEPU(1)  BSTEPU(2)  BSTEPU(3)  BSTEPU(4)  BSTEPU(5)  BSTEPU(6)  BSTEPU(7) \
      BSTEPU(8)  BSTEPU(9)  BSTEPU(10) BSTEPU(11) BSTEPU(12) BSTEPU(13) BSTEPU(14) BSTEPU(15) \
    } else { \
      BSTEPM(0)  BSTEPM(1)  BSTEPM(2)  BSTEPM(3)  BSTEPM(4)  BSTEPM(5)  BSTEPM(6)  BSTEPM(7) \
      BSTEPM(8)  BSTEPM(9)  BSTEPM(10) BSTEPM(11) BSTEPM(12) BSTEPM(13) BSTEPM(14) BSTEPM(15) \
    } \
  }

    BISSUE(0, ra) BISSUE(1, rb) BISSUE(2, rc)
    int j = 0;
    for (; j + 3 <= nwB; j += 3) {
      BBODY(j, ra) BBODY(j + 1, rb) BBODY(j + 2, rc)
    }
    if (j < nwB) { BBODY(j, ra) ++j; }
    if (j < nwB) { BBODY(j, rb) ++j; }
#undef BBODY
#undef BPREP
#undef BSTEPM
#undef BSTEPU
#undef BISSUE
#undef BLD
    RESCALE45(G0, G1, G2, ctotB)

    sG0v[lane] = G0;
    sG1v[lane] = G1;
    if (is63) sG2s = G2;
    if (lane == 0) sCtB = ctotB;

  } else {
    // ================= LSE waves (2..5): async row-LSE streaming =================
    const int pw = wv - 2;
    const int prow = lane >> 4;
    const int pcol = (lane & 15) << 2;
    const float* pb_ = lg + ((((pw << 2) + prow) << 6) + pcol);
    float acc = 0.0f;
    float4 pa, pb, pc;

#define LISSUE(K, S) { S = *(const float4*)(pb_ + ((K) << 10)); }

#define LBODY(K, S) { \
    const float e0 = __builtin_amdgcn_exp2f(S.x * LOG2E); \
    const float e1 = __builtin_amdgcn_exp2f(S.y * LOG2E); \
    const float e2 = __builtin_amdgcn_exp2f(S.z * LOG2E); \
    const float e3 = __builtin_amdgcn_exp2f(S.w * LOG2E); \
    if ((K) + 3 < 64) { LISSUE((K) + 3, S) } \
    float s = (e0 + e1) + (e2 + e3); \
    s += i2f(__builtin_amdgcn_update_dpp(0, f2i(s), 0x111, 0xF, 0xF, true)); \
    s += i2f(__builtin_amdgcn_update_dpp(0, f2i(s), 0x112, 0xF, 0xF, true)); \
    s += i2f(__builtin_amdgcn_update_dpp(0, f2i(s), 0x114, 0xF, 0xF, true)); \
    s += i2f(__builtin_amdgcn_update_dpp(0, f2i(s), 0x118, 0xF, 0xF, true)); \
    if ((lane & 15) == 15 && ((((K) << 4) + (pw << 2) + prow) < len)) acc += __logf(s); \
  }

    LISSUE(0, pa) LISSUE(1, pb) LISSUE(2, pc)
    int k = 0;
    for (; k + 3 <= nwin; k += 3) {
      LBODY(k, pa) LBODY(k + 1, pb) LBODY(k + 2, pc)
    }
    if (k < nwin) { LBODY(k, pa) ++k; }
    if (k < nwin) { LBODY(k, pb) ++k; }
#undef LBODY
#undef LISSUE

    float a = ((lane & 15) == 15) ? acc : 0.0f;
    a += __shfl_xor(a, 16);
    a += __shfl_xor(a, 32);
    if (lane == 63) lsePart[pw] = a;
  }

  __syncthreads();   // single block-wide sync of the whole kernel

  if (wv == 0) {
    // p = sum_s alpha_{mid-1}(s) * gamma_mid(s); both rescaled to <= 2^45
    float prod = A0 * sG0v[lane] + A1 * sG1v[lane];
    if (lane == 63) prod = fmaf(A2, sG2s, prod);
#pragma unroll
    for (int off = 32; off; off >>= 1) prod += __shfl_xor(prod, off);
    const float p = fmaxf(prod, 1e-37f);   // guard: never log(0) -> inf poisoning
    float loss = ((lsePart[0] + lsePart[1]) + (lsePart[2] + lsePart[3]))
               - LN2 * (__builtin_amdgcn_logf(p) - (float)(ctotA + sCtB));
    if (lab_len > len) loss = 0.0f;  // feasibility mask
    if (lane == 0) atomicAdd(out, loss * (1.0f / 256.0f));
  }
#undef RESCALE45
#undef RENORM3
}

extern "C" void kernel_launch(void* const* d_in, const int* in_sizes, int n_in,
                              void* d_out, int out_size, void* d_ws, size_t ws_size,
                              hipStream_t stream) {
  (void)in_sizes; (void)n_in; (void)out_size; (void)d_ws; (void)ws_size;
  hipMemsetAsync(d_out, 0, sizeof(float), stream);   // d_out is poisoned 0xAA
  ctc_fused<<<dim3(BB), dim3(384), 0, stream>>>(
      (const int*)d_in[0], (const float*)d_in[1], (const int*)d_in[2], (float*)d_out);
}